// Round 10
// baseline (737.828 us; speedup 1.0000x reference)
//
#include <hip/hip_runtime.h>

#define T_STEPS 1024
#define BATCH 2048
#define BTILE 4
#define HS 36   // LDS row stride in u32 words; 36 % 32 == 4 -> conflict-free b128 reads

typedef short short8 __attribute__((ext_vector_type(8)));
typedef float f32x4 __attribute__((ext_vector_type(4)));
typedef float f32x2 __attribute__((ext_vector_type(2)));

__device__ __forceinline__ float fast_rcp(float x) {
#if __has_builtin(__builtin_amdgcn_rcpf)
    return __builtin_amdgcn_rcpf(x);
#else
    return 1.0f / x;
#endif
}

__device__ __forceinline__ float fast_exp2(float x) {
#if __has_builtin(__builtin_amdgcn_exp2f)
    return __builtin_amdgcn_exp2f(x);
#else
    return exp2f(x);
#endif
}

__device__ __forceinline__ float sigf(float x) {
    return fast_rcp(1.0f + fast_exp2(-1.44269504f * x));
}

// packed 2-lane sigmoid
__device__ __forceinline__ f32x2 sigf2(f32x2 v) {
    f32x2 t = v * (-1.44269504f);
    f32x2 e = {fast_exp2(t[0]), fast_exp2(t[1])};
    e = e + 1.0f;
    return f32x2{fast_rcp(e[0]), fast_rcp(e[1])};
}

__device__ __forceinline__ float tanh_fast(float x) {
    float e = fast_exp2(2.88539008f * x);
    return 1.0f - 2.0f * fast_rcp(e + 1.0f);
}

// float -> bf16 bits (round-to-nearest-even) — setup only
__device__ __forceinline__ unsigned f2bf(float x) {
    unsigned u = __float_as_uint(x);
    unsigned r = u + 0x7FFFu + ((u >> 16) & 1u);
    return r >> 16;
}
__device__ __forceinline__ float bf2f(unsigned b) {
    return __uint_as_float(b << 16);
}

// packed bf16 convert: dst = {hi16=bf16(b), lo16=bf16(a)}, RNE
__device__ __forceinline__ unsigned cvt_pk_bf16(float a, float b) {
    unsigned r;
    asm("v_cvt_pk_bf16_f32 %0, %1, %2" : "=v"(r) : "v"(a), "v"(b));
    return r;
}

// DPP conventions (HW-validated R2-R9): 0x110+N: lane l <- lane l-N (row-16);
// 0x100+N: lane l <- lane l+N. bank_mask: unselected banks keep OLD dst value.
__device__ __forceinline__ float sel4A(f32x4 a) {
    int v = __float_as_int(a[0]);                                        // bank 0 (r=0)
    v = __builtin_amdgcn_update_dpp(v, __float_as_int(a[1]), 0x114, 0xf, 0x2, false);
    v = __builtin_amdgcn_update_dpp(v, __float_as_int(a[2]), 0x118, 0xf, 0x4, false);
    v = __builtin_amdgcn_update_dpp(v, __float_as_int(a[3]), 0x11C, 0xf, 0x8, false);
    return __int_as_float(v);
}
__device__ __forceinline__ float dpp_shl4f(float v) {
    return __int_as_float(__builtin_amdgcn_update_dpp(0, __float_as_int(v), 0x104, 0xf, 0xf, true));
}

// R7 structure (4 waves / 4 batches / 512 blocks / 2 per CU) with SKEW-FREE
// layer-2: every wave computes L2 redundantly each step (6 extra MFMAs land
// on the idle MFMA pipe; ~+80 VALU cyc paid from idle slots). All waves are
// now identical -> no round-robin straggler at the barrier, and the Lst LDS
// handoff is gone (h1/c1 live in lane registers of lanes 0..3 of every wave).
__global__ __launch_bounds__(256, 2)
void lstm_v10_kernel(const float* __restrict__ input,
                     const float* __restrict__ W_ih0,
                     const float* __restrict__ W_hh0,
                     const float* __restrict__ b_ih0,
                     const float* __restrict__ b_hh0,
                     const float* __restrict__ W_ih1,
                     const float* __restrict__ W_hh1,
                     const float* __restrict__ b_ih1,
                     const float* __restrict__ b_hh1,
                     float* __restrict__ out)
{
    const int tid = threadIdx.x;
    const int w   = tid >> 6;
    const int l   = tid & 63;
    const int q16 = l >> 4;
    const int n16 = l & 15;
    const int nb  = l & 3;
    const int r   = (l >> 2) & 3;
    const int u   = 16 * w + 4 * q16 + r;
    const int bbase = blockIdx.x * BTILE;

    __shared__ __align__(16) unsigned Hbuf[2][3][16][HS];   // 13.8 KB
    __shared__ float Xb[2][BTILE][65];

    for (int i = tid; i < 2 * 3 * 16 * HS; i += 256)
        reinterpret_cast<unsigned*>(Hbuf)[i] = 0u;

    // ---- L1 A-fragments: a1[g][kt] = W_hh0 tile (w+4g, kt) ----
    short8 a1[4][2];
    #pragma unroll
    for (int g = 0; g < 4; ++g) {
        #pragma unroll
        for (int kt = 0; kt < 2; ++kt) {
            const float* p = W_hh0 + (size_t)(16 * (w + 4 * g) + n16) * 64 + kt * 32 + q16 * 8;
            short8 a;
            #pragma unroll
            for (int j = 0; j < 8; ++j) a[j] = (short)f2bf(p[j]);
            a1[g][kt] = a;
        }
    }
    // ---- L2 A-fragments (hi/lo split), rows m>=4 zero ----
    short8 a2h[2], a2l[2];
    #pragma unroll
    for (int kt = 0; kt < 2; ++kt) {
        short8 ah = {0,0,0,0,0,0,0,0}, al = {0,0,0,0,0,0,0,0};
        if (n16 < 4) {
            const float* p = W_ih1 + (size_t)n16 * 64 + kt * 32 + q16 * 8;
            #pragma unroll
            for (int j = 0; j < 8; ++j) {
                unsigned hb = f2bf(p[j]);
                ah[j] = (short)hb;
                al[j] = (short)f2bf(p[j] - bf2f(hb));
            }
        }
        a2h[kt] = ah; a2l[kt] = al;
    }

    // activation constants for cell (nb, u), packed as float2 pairs
    f32x2 w01, w23, b01, b23;
    {
        float wgv[4], bgv[4];
        #pragma unroll
        for (int g = 0; g < 4; ++g) {
            int row = g * 64 + u;
            wgv[g] = W_ih0[row];
            bgv[g] = b_ih0[row] + b_hh0[row];
        }
        w01 = f32x2{wgv[0], wgv[1]}; w23 = f32x2{wgv[2], wgv[3]};
        b01 = f32x2{bgv[0], bgv[1]}; b23 = f32x2{bgv[2], bgv[3]};
    }
    float whh1v[4], b1v[4];
    #pragma unroll
    for (int g = 0; g < 4; ++g) { whh1v[g] = W_hh1[g]; b1v[g] = b_ih1[g] + b_hh1[g]; }

    const float* inrow = input + (size_t)(bbase + w) * T_STEPS;
    Xb[0][w][l] = inrow[l];
    float xnext = 0.0f;
    float c0 = 0.0f;
    float h1r = 0.0f, c1r = 0.0f;   // L2 state for batch l (valid at l<4), per wave

    __syncthreads();

    int par = 0;
    #pragma unroll 2
    for (int t = 0; t < T_STEPS; ++t) {
        if ((t & 63) == 0 && t + 64 < T_STEPS) xnext = inrow[t + 64 + l];
        const int cp = (t >> 6) & 1;

        // ---- B-fragments: h(t-1) ----
        const unsigned* Hrow = &Hbuf[par][0][n16][0];
        short8 hb0 = *reinterpret_cast<const short8*>(Hrow + 4 * q16);
        short8 hb1 = *reinterpret_cast<const short8*>(Hrow + 16 + 4 * q16);

        // ---- L1 MFMA ----
        f32x4 accv[4];
        #pragma unroll
        for (int g = 0; g < 4; ++g) {
            f32x4 z = {0.0f, 0.0f, 0.0f, 0.0f};
            z = __builtin_amdgcn_mfma_f32_16x16x32_bf16(a1[g][0], hb0, z, 0, 0, 0);
            z = __builtin_amdgcn_mfma_f32_16x16x32_bf16(a1[g][1], hb1, z, 0, 0, 0);
            accv[g] = z;
        }

        // ---- layer-2 for step t-1: ALL waves, redundantly (no straggler) ----
        if (t > 0) {
            const unsigned* Ch = &Hbuf[par][1][n16][0];
            const unsigned* Cl = &Hbuf[par][2][n16][0];
            short8 ch0 = *reinterpret_cast<const short8*>(Ch + 4 * q16);
            short8 ch1 = *reinterpret_cast<const short8*>(Ch + 16 + 4 * q16);
            short8 cl0 = *reinterpret_cast<const short8*>(Cl + 4 * q16);
            short8 cl1 = *reinterpret_cast<const short8*>(Cl + 16 + 4 * q16);
            f32x4 zA = {0.0f, 0.0f, 0.0f, 0.0f};
            f32x4 zB = {0.0f, 0.0f, 0.0f, 0.0f};
            zA = __builtin_amdgcn_mfma_f32_16x16x32_bf16(a2h[0], ch0, zA, 0, 0, 0);
            zB = __builtin_amdgcn_mfma_f32_16x16x32_bf16(a2l[1], ch1, zB, 0, 0, 0);
            zA = __builtin_amdgcn_mfma_f32_16x16x32_bf16(a2h[1], ch1, zA, 0, 0, 0);
            zB = __builtin_amdgcn_mfma_f32_16x16x32_bf16(a2h[0], cl0, zB, 0, 0, 0);
            zA = __builtin_amdgcn_mfma_f32_16x16x32_bf16(a2l[0], ch0, zA, 0, 0, 0);
            zB = __builtin_amdgcn_mfma_f32_16x16x32_bf16(a2h[1], cl1, zB, 0, 0, 0);
            f32x4 z = zA + zB;           // lanes 0..3: rows=gates, col=batch l
            if (l < 4) {
                float g1i = z[0] + b1v[0] + h1r * whh1v[0];
                float g1f = z[1] + b1v[1] + h1r * whh1v[1];
                float g1g = z[2] + b1v[2] + h1r * whh1v[2];
                float g1o = z[3] + b1v[3] + h1r * whh1v[3];
                float c1n = sigf(g1f) * c1r + sigf(g1i) * tanh_fast(g1g);
                float h1n = sigf(g1o) * tanh_fast(c1n);
                c1r = c1n;
                h1r = h1n;
                if (w == 0)              // all waves hold identical values
                    out[(size_t)(bbase + l) * T_STEPS + (t - 1)] = c1n;
            }
        }

        // ---- in-register gate redistribution (bank-masked DPP, 12 inst) ----
        float g4[4];
        #pragma unroll
        for (int g = 0; g < 4; ++g) g4[g] = sel4A(accv[g]);

        // ---- layer-1 activation for cell (nb, u), packed math ----
        float x = Xb[cp][nb][t & 63];
        f32x2 xx = {x, x};
        f32x2 gif = f32x2{g4[0], g4[1]} + (xx * w01 + b01);   // (i, f)
        f32x2 ggo = f32x2{g4[2], g4[3]} + (xx * w23 + b23);   // (g, o)

        f32x2 sif = sigf2(gif);                  // sig(i), sig(f)
        float tg  = tanh_fast(ggo[0]);
        float c0n = sif[1] * c0 + sif[0] * tg;
        c0 = c0n;
        float h0n = sigf(ggo[1]) * tanh_fast(c0n);

        // ---- pack h / c0hi / c0lo pairs via v_cvt_pk_bf16_f32 ----
        float ph = dpp_shl4f(h0n);               // partner unit u+1 (lane l+4)
        float pc = dpp_shl4f(c0n);
        unsigned hword  = cvt_pk_bf16(h0n, ph);  // lo=own, hi=partner
        unsigned chword = cvt_pk_bf16(c0n, pc);
        float hi_own = bf2f(chword & 0xFFFFu);   // own bf16(c0n) as f32
        float lo_own = c0n - hi_own;
        float plo = dpp_shl4f(lo_own);
        unsigned clword = cvt_pk_bf16(lo_own, plo);
        if (!(l & 4)) {                          // r even: owns pair (u, u+1)
            int widx = 8 * w + 2 * q16 + (r >> 1);
            Hbuf[par ^ 1][0][nb][widx] = hword;
            Hbuf[par ^ 1][1][nb][widx] = chword;
            Hbuf[par ^ 1][2][nb][widx] = clword;
        }
        if ((t & 63) == 63 && t + 1 < T_STEPS) Xb[cp ^ 1][w][l] = xnext;

        __syncthreads();
        par ^= 1;
    }

    // ---- epilogue: layer-2 for step 1023 (wave 0, register state) ----
    if (w == 0) {
        const unsigned* Ch = &Hbuf[par][1][n16][0];
        const unsigned* Cl = &Hbuf[par][2][n16][0];
        short8 ch0 = *reinterpret_cast<const short8*>(Ch + 4 * q16);
        short8 ch1 = *reinterpret_cast<const short8*>(Ch + 16 + 4 * q16);
        short8 cl0 = *reinterpret_cast<const short8*>(Cl + 4 * q16);
        short8 cl1 = *reinterpret_cast<const short8*>(Cl + 16 + 4 * q16);
        f32x4 zA = {0.0f, 0.0f, 0.0f, 0.0f};
        f32x4 zB = {0.0f, 0.0f, 0.0f, 0.0f};
        zA = __builtin_amdgcn_mfma_f32_16x16x32_bf16(a2h[0], ch0, zA, 0, 0, 0);
        zB = __builtin_amdgcn_mfma_f32_16x16x32_bf16(a2l[1], ch1, zB, 0, 0, 0);
        zA = __builtin_amdgcn_mfma_f32_16x16x32_bf16(a2h[1], ch1, zA, 0, 0, 0);
        zB = __builtin_amdgcn_mfma_f32_16x16x32_bf16(a2h[0], cl0, zB, 0, 0, 0);
        zA = __builtin_amdgcn_mfma_f32_16x16x32_bf16(a2l[0], ch0, zA, 0, 0, 0);
        zB = __builtin_amdgcn_mfma_f32_16x16x32_bf16(a2h[1], cl1, zB, 0, 0, 0);
        f32x4 z = zA + zB;
        if (l < 4) {
            float g1i = z[0] + b1v[0] + h1r * whh1v[0];
            float g1f = z[1] + b1v[1] + h1r * whh1v[1];
            float g1g = z[2] + b1v[2] + h1r * whh1v[2];
            float g1o = z[3] + b1v[3] + h1r * whh1v[3];
            float c1n = sigf(g1f) * c1r + sigf(g1i) * tanh_fast(g1g);
            out[(size_t)(bbase + l) * T_STEPS + (T_STEPS - 1)] = c1n;
        }
    }
}

extern "C" void kernel_launch(void* const* d_in, const int* in_sizes, int n_in,
                              void* d_out, int out_size, void* d_ws, size_t ws_size,
                              hipStream_t stream) {
    const float* input = (const float*)d_in[0];
    const float* W_ih0 = (const float*)d_in[1];
    const float* W_hh0 = (const float*)d_in[2];
    const float* b_ih0 = (const float*)d_in[3];
    const float* b_hh0 = (const float*)d_in[4];
    const float* W_ih1 = (const float*)d_in[5];
    const float* W_hh1 = (const float*)d_in[6];
    const float* b_ih1 = (const float*)d_in[7];
    const float* b_hh1 = (const float*)d_in[8];
    float* out = (float*)d_out;

    dim3 grid(BATCH / BTILE);   // 512 blocks -> 2 blocks/CU, 2 waves/SIMD
    dim3 block(256);
    lstm_v10_kernel<<<grid, block, 0, stream>>>(
        input, W_ih0, W_hh0, b_ih0, b_hh0, W_ih1, W_hh1, b_ih1, b_hh1, out);
}